// Round 5
// baseline (636.737 us; speedup 1.0000x reference)
//
#include <hip/hip_runtime.h>
#include <hip/hip_bf16.h>
#include <math.h>

#define N_NODES 100000
#define N_PAD 100032   // padded row count for workspace feature buffers
#define N_EDGES 1600000
#define HID 128
#define N_CLASS 10

// edge partition params
#define NR 8           // dst ranges (one per XCD)
#define RANGE 12512    // 8 * 12512 >= N_NODES
#define PCAP 400000    // per-range packed-edge capacity (expected ~200K)
#define P_BLOCKS 512
#define P_SLICE (N_EDGES / P_BLOCKS)  // 3125

typedef float f32x4 __attribute__((ext_vector_type(4)));
typedef short short8 __attribute__((ext_vector_type(8)));
typedef unsigned short us4 __attribute__((ext_vector_type(4)));

// bf16 helpers (round-to-nearest-even)
__device__ __forceinline__ unsigned short f2bf(float x) {
    unsigned u = __float_as_uint(x);
    unsigned r = u + 0x7FFF + ((u >> 16) & 1);
    return (unsigned short)(r >> 16);
}
__device__ __forceinline__ float bf2f(unsigned short h) {
    return __uint_as_float(((unsigned)h) << 16);
}
__device__ __forceinline__ float elu(float x) {
    return x > 0.f ? x : (expf(x) - 1.f);
}

// ---------------------------------------------------------------------------
// CSR build: histogram -> hierarchical exclusive scan -> two-pass fill
// ---------------------------------------------------------------------------

__global__ void count_k(const int* __restrict__ dst, int* __restrict__ cnt) {
    int e = blockIdx.x * blockDim.x + threadIdx.x;
    if (e < N_EDGES) atomicAdd(&cnt[dst[e]], 1);
}

__global__ void scan1_k(const int* __restrict__ in, int* __restrict__ out,
                        int* __restrict__ bsum) {
    __shared__ int sh[256];
    int base = blockIdx.x * 1024 + threadIdx.x * 4;
    int v[4];
    int s = 0;
#pragma unroll
    for (int i = 0; i < 4; i++) {
        int idx = base + i;
        v[i] = (idx < N_NODES) ? in[idx] : 0;
        s += v[i];
    }
    sh[threadIdx.x] = s;
    __syncthreads();
    for (int off = 1; off < 256; off <<= 1) {
        int t = (threadIdx.x >= off) ? sh[threadIdx.x - off] : 0;
        __syncthreads();
        sh[threadIdx.x] += t;
        __syncthreads();
    }
    int excl = sh[threadIdx.x] - s;
    if (threadIdx.x == 255) bsum[blockIdx.x] = sh[255];
    int run = excl;
#pragma unroll
    for (int i = 0; i < 4; i++) {
        int idx = base + i;
        if (idx < N_NODES) out[idx] = run;
        run += v[i];
    }
}

__global__ void scan2_k(int* __restrict__ bsum, int nb) {
    __shared__ int sh[256];
    int v = (threadIdx.x < nb) ? bsum[threadIdx.x] : 0;
    sh[threadIdx.x] = v;
    __syncthreads();
    for (int off = 1; off < 256; off <<= 1) {
        int t = (threadIdx.x >= off) ? sh[threadIdx.x - off] : 0;
        __syncthreads();
        sh[threadIdx.x] += t;
        __syncthreads();
    }
    if (threadIdx.x < nb) bsum[threadIdx.x] = sh[threadIdx.x] - v;  // exclusive
}

__global__ void scan3_k(int* __restrict__ row_ptr, const int* __restrict__ bsum,
                        int* __restrict__ cursor) {
    int i = blockIdx.x * blockDim.x + threadIdx.x;
    if (i < N_NODES) {
        int v = row_ptr[i] + bsum[i >> 10];
        row_ptr[i] = v;
        cursor[i] = v;
    }
    if (i == 0) row_ptr[N_NODES] = N_EDGES;
}

// Pass 1: partition edges into NR dst-range buckets, packed src|(dloc<<17).
// Per-block LDS stash + histogram + chunk claim -> contiguous global writes.
__global__ __launch_bounds__(256) void partition_k(const int* __restrict__ src,
                                                   const int* __restrict__ dst,
                                                   int* __restrict__ gbase,
                                                   unsigned* __restrict__ gbuf) {
    __shared__ unsigned stash[P_SLICE];
    __shared__ unsigned char rbuf[P_SLICE];
    __shared__ int hist[NR], cur[NR], base[NR];
    if (threadIdx.x < NR) { hist[threadIdx.x] = 0; cur[threadIdx.x] = 0; }
    __syncthreads();
    const int e0 = blockIdx.x * P_SLICE;
    for (int i = threadIdx.x; i < P_SLICE; i += 256) {
        int s = src[e0 + i];
        int d = dst[e0 + i];
        unsigned r = (unsigned)d / RANGE;      // constant div -> magic mul
        unsigned dloc = (unsigned)d - r * RANGE;
        stash[i] = (unsigned)s | (dloc << 17);
        rbuf[i] = (unsigned char)r;
        atomicAdd(&hist[r], 1);
    }
    __syncthreads();
    if (threadIdx.x < NR)
        base[threadIdx.x] = atomicAdd(&gbase[threadIdx.x], hist[threadIdx.x]);
    __syncthreads();
    for (int i = threadIdx.x; i < P_SLICE; i += 256) {
        unsigned r = rbuf[i];
        int off = atomicAdd(&cur[r], 1);
        int pos = base[r] + off;
        if (pos < PCAP) gbuf[(size_t)r * PCAP + pos] = stash[i];
    }
}

// Pass 2: fill col within each dst range. Block b -> range b&7 (XCD
// round-robin); per-XCD working set (packed reads + col writes + cursor)
// is L2-resident -> write merging.
__global__ __launch_bounds__(256) void fill2_k(const unsigned* __restrict__ gbuf,
                                               const int* __restrict__ gbase,
                                               int* __restrict__ cursor,
                                               int* __restrict__ col) {
    const int r = blockIdx.x & 7;
    const int sub = blockIdx.x >> 3;          // 0..31
    const int n = gbase[r];
    const unsigned* buf = gbuf + (size_t)r * PCAP;
    const int node0 = r * RANGE;
    const int per = (n + 31) / 32;
    const int i0 = sub * per;
    const int i1 = min(n, i0 + per);
    for (int i = i0 + threadIdx.x; i < i1; i += 256) {
        unsigned w = buf[i];
        int s = (int)(w & 0x1FFFF);
        int d = node0 + (int)(w >> 17);
        int slot = atomicAdd(&cursor[d], 1);
        col[slot] = s;
    }
}

// ---------------------------------------------------------------------------
// fp32 -> bf16 cast of x (layer-1 gather source)
// ---------------------------------------------------------------------------
__global__ __launch_bounds__(256) void cast_k(const float* __restrict__ x,
                                              unsigned short* __restrict__ hb) {
    int i = blockIdx.x * blockDim.x + threadIdx.x;  // float4 index
    if (i < N_NODES * (HID / 4)) {
        float4 v = ((const float4*)x)[i];
        us4 o = {f2bf(v.x), f2bf(v.y), f2bf(v.z), f2bf(v.w)};
        ((us4*)hb)[i] = o;
    }
}

// ---------------------------------------------------------------------------
// Weight pre-split + pre-pack into MFMA B-fragment order.
// ---------------------------------------------------------------------------
__global__ void wsplit_k(const float* __restrict__ Wa, const float* __restrict__ Wb,
                         unsigned short* __restrict__ Whp,
                         unsigned short* __restrict__ Wlp) {
    int f = blockIdx.x * blockDim.x + threadIdx.x;
    if (f >= 6 * 16384) return;
    int g = f >> 14;
    int r = f & 16383;
    int j = r & 7;
    int L = (r >> 3) & 63;
    int t = r >> 9;          // kb*8 + nt
    int kb = t >> 3, nt = t & 7;
    int k = kb * 32 + ((L >> 4) & 3) * 8 + j;
    int n = nt * 16 + (L & 15);
    int layer = g >> 1;
    const float* W = (g & 1) ? Wb : Wa;
    float w = W[layer * 16384 + k * 128 + n];
    unsigned short hi = f2bf(w);
    unsigned short lo = f2bf(w - bf2f(hi));
    Whp[f] = hi;
    Wlp[f] = lo;
}

// ---------------------------------------------------------------------------
// Aggregation: one HALF-WAVE (32 lanes) per node, bf16 rows (256B), us4/lane.
// fp32 accumulate. z[n] = h[n] + sum_{s in N(n)} h[s]
// ---------------------------------------------------------------------------
__device__ __forceinline__ float4 us4f(us4 v) {
    float4 o;
    o.x = bf2f(v.x); o.y = bf2f(v.y); o.z = bf2f(v.z); o.w = bf2f(v.w);
    return o;
}

__global__ __launch_bounds__(256) void agg_k(const unsigned short* __restrict__ h,
                                             const int* __restrict__ row_ptr,
                                             const int* __restrict__ col,
                                             float* __restrict__ z) {
    const int half = (blockIdx.x * blockDim.x + threadIdx.x) >> 5;  // node id
    const int lane = threadIdx.x & 31;
    const int halfbase = threadIdx.x & 32;
    if (half >= N_NODES) return;
    const us4* hp = (const us4*)h;  // 32 x us4 per row
    float4 acc = us4f(hp[(size_t)half * 32 + lane]);  // self term, (1+eps)=1
    const int beg = row_ptr[half];
    const int end = row_ptr[half + 1];

    for (int base = beg; base < end; base += 32) {
        const int n = min(32, end - base);
        int myidx = (lane < n) ? col[base + lane] : 0;
        int j = 0;
        for (; j + 4 <= n; j += 4) {
            int i0 = __shfl(myidx, halfbase + j + 0, 64);
            int i1 = __shfl(myidx, halfbase + j + 1, 64);
            int i2 = __shfl(myidx, halfbase + j + 2, 64);
            int i3 = __shfl(myidx, halfbase + j + 3, 64);
            float4 v0 = us4f(hp[(size_t)i0 * 32 + lane]);
            float4 v1 = us4f(hp[(size_t)i1 * 32 + lane]);
            float4 v2 = us4f(hp[(size_t)i2 * 32 + lane]);
            float4 v3 = us4f(hp[(size_t)i3 * 32 + lane]);
            acc.x += v0.x; acc.y += v0.y; acc.z += v0.z; acc.w += v0.w;
            acc.x += v1.x; acc.y += v1.y; acc.z += v1.z; acc.w += v1.w;
            acc.x += v2.x; acc.y += v2.y; acc.z += v2.z; acc.w += v2.w;
            acc.x += v3.x; acc.y += v3.y; acc.z += v3.z; acc.w += v3.w;
        }
        for (; j < n; j++) {
            int i0 = __shfl(myidx, halfbase + j, 64);
            float4 v0 = us4f(hp[(size_t)i0 * 32 + lane]);
            acc.x += v0.x; acc.y += v0.y; acc.z += v0.z; acc.w += v0.w;
        }
    }
    ((float4*)z)[(size_t)half * 32 + lane] = acc;  // fp32 out, 32 float4/row
}

// ---------------------------------------------------------------------------
// MFMA MLP: h_out(bf16) = ELU(ELU(z@Wa + ba)@Wb + bb), split-bf16 x3 terms.
// ---------------------------------------------------------------------------
__device__ __forceinline__ void gemm_phase(
    const unsigned short* Aph_, const unsigned short* Apl_,
    const unsigned short* Wph_, const unsigned short* __restrict__ Wlo_g,
    const float* __restrict__ bias, int tid, f32x4 acc[2][4]) {
    const int L = tid & 63;
    const int w = tid >> 6;
    const int mt0 = (w >> 1) * 2;
    const int nt0 = (w & 1) * 4;
    const int lan15 = L & 15;
#pragma unroll
    for (int n = 0; n < 4; n++) {
        float b = bias[(nt0 + n) * 16 + lan15];
        f32x4 bv = {b, b, b, b};
        acc[0][n] = bv;
        acc[1][n] = bv;
    }
#pragma unroll
    for (int kb = 0; kb < 4; kb++) {
        short8 ah0 = *(const short8*)&Aph_[(((mt0 + 0) * 4 + kb) * 64 + L) * 8];
        short8 ah1 = *(const short8*)&Aph_[(((mt0 + 1) * 4 + kb) * 64 + L) * 8];
        short8 al0 = *(const short8*)&Apl_[(((mt0 + 0) * 4 + kb) * 64 + L) * 8];
        short8 al1 = *(const short8*)&Apl_[(((mt0 + 1) * 4 + kb) * 64 + L) * 8];
#pragma unroll
        for (int n = 0; n < 4; n++) {
            int widx = ((kb * 8 + nt0 + n) * 64 + L) * 8;
            short8 bh = *(const short8*)&Wph_[widx];
            short8 bl = *(const short8*)&Wlo_g[widx];
            acc[0][n] = __builtin_amdgcn_mfma_f32_16x16x32_bf16(ah0, bh, acc[0][n], 0, 0, 0);
            acc[1][n] = __builtin_amdgcn_mfma_f32_16x16x32_bf16(ah1, bh, acc[1][n], 0, 0, 0);
            acc[0][n] = __builtin_amdgcn_mfma_f32_16x16x32_bf16(al0, bh, acc[0][n], 0, 0, 0);
            acc[1][n] = __builtin_amdgcn_mfma_f32_16x16x32_bf16(al1, bh, acc[1][n], 0, 0, 0);
            acc[0][n] = __builtin_amdgcn_mfma_f32_16x16x32_bf16(ah0, bl, acc[0][n], 0, 0, 0);
            acc[1][n] = __builtin_amdgcn_mfma_f32_16x16x32_bf16(ah1, bl, acc[1][n], 0, 0, 0);
        }
    }
}

__global__ __launch_bounds__(256) void mlp2_k(
    const float* __restrict__ zin,
    const unsigned short* __restrict__ Wahp, const unsigned short* __restrict__ Walp,
    const unsigned short* __restrict__ Wbhp, const unsigned short* __restrict__ Wblp,
    const float* __restrict__ ba, const float* __restrict__ bb,
    unsigned short* __restrict__ hout) {
    __shared__ unsigned short Aph[8192];   // 16 KB: packed A hi
    __shared__ unsigned short Apl[8192];   // 16 KB: packed A lo
    __shared__ unsigned short Wph[16384];  // 32 KB: packed W hi

    const int tid = threadIdx.x;
    const int L = tid & 63;
    const int w = tid >> 6;
    const int mt0 = (w >> 1) * 2;
    const int nt0 = (w & 1) * 4;
    const int lan15 = L & 15;
    const int quad = L >> 4;
    const size_t node_base = (size_t)blockIdx.x * 64;

    // ---- phase A: load z tile, split to bf16 hi/lo, pack to A-frag layout;
    //      stage Wa-hi into LDS ----
    {
        const float4* zin4 = (const float4*)(zin + node_base * HID);
#pragma unroll
        for (int r = 0; r < 8; r++) {
            int f = tid + 256 * r;          // [0, 2048)
            int m = f >> 5;
            int k0 = (f & 31) * 4;
            float4 zv = zin4[f];
            int kb = k0 >> 5;
            int q = (k0 & 31) >> 3;
            int j0 = k0 & 7;                 // 0 or 4
            int idx = (((m >> 4) * 4 + kb) * 64 + ((m & 15) + 16 * q)) * 8 + j0;
            unsigned short hx = f2bf(zv.x), hy = f2bf(zv.y),
                           hz = f2bf(zv.z), hw = f2bf(zv.w);
            us4 h4 = {hx, hy, hz, hw};
            us4 l4 = {f2bf(zv.x - bf2f(hx)), f2bf(zv.y - bf2f(hy)),
                      f2bf(zv.z - bf2f(hz)), f2bf(zv.w - bf2f(hw))};
            *(us4*)&Aph[idx] = h4;
            *(us4*)&Apl[idx] = l4;
        }
        const uint4* wsrc = (const uint4*)Wahp;
        uint4* wdst = (uint4*)Wph;
#pragma unroll
        for (int r = 0; r < 8; r++) wdst[tid + 256 * r] = wsrc[tid + 256 * r];
    }
    __syncthreads();

    // ---- GEMM1: t = ELU(z @ Wa + ba) ----
    {
        f32x4 acc[2][4];
        gemm_phase(Aph, Apl, Wph, Walp, ba, tid, acc);
        __syncthreads();  // all waves done reading A/W frags
#pragma unroll
        for (int i = 0; i < 2; i++) {
#pragma unroll
            for (int n = 0; n < 4; n++) {
                int kdim = (nt0 + n) * 16 + lan15;
                int kb2 = kdim >> 5;
                int q2 = (kdim & 31) >> 3;
                int j2 = kdim & 7;
#pragma unroll
                for (int r = 0; r < 4; r++) {
                    float v = elu(acc[i][n][r]);
                    int mrow = quad * 4 + r;
                    unsigned short hi = f2bf(v);
                    unsigned short lo = f2bf(v - bf2f(hi));
                    int idx = (((mt0 + i) * 4 + kb2) * 64 + (mrow + 16 * q2)) * 8 + j2;
                    Aph[idx] = hi;
                    Apl[idx] = lo;
                }
            }
        }
        const uint4* wsrc = (const uint4*)Wbhp;
        uint4* wdst = (uint4*)Wph;
#pragma unroll
        for (int r = 0; r < 8; r++) wdst[tid + 256 * r] = wsrc[tid + 256 * r];
    }
    __syncthreads();

    // ---- GEMM2: h = ELU(t @ Wb + bb), bf16 store ----
    {
        f32x4 acc[2][4];
        gemm_phase(Aph, Apl, Wph, Wblp, bb, tid, acc);
#pragma unroll
        for (int i = 0; i < 2; i++) {
#pragma unroll
            for (int n = 0; n < 4; n++) {
                int ncol = (nt0 + n) * 16 + lan15;
#pragma unroll
                for (int r = 0; r < 4; r++) {
                    int mrow = (mt0 + i) * 16 + quad * 4 + r;
                    hout[(node_base + mrow) * HID + ncol] = f2bf(elu(acc[i][n][r]));
                }
            }
        }
    }
}

// ---------------------------------------------------------------------------
// Final FC: out = h(bf16) @ fcW + fcb   [100k x 10]
// ---------------------------------------------------------------------------
__global__ __launch_bounds__(256) void fc_k(const unsigned short* __restrict__ h,
                                            const float* __restrict__ fcW,
                                            const float* __restrict__ fcb,
                                            float* __restrict__ out) {
    __shared__ float ht[64][HID + 4];
    size_t nb = (size_t)blockIdx.x * 64;
#pragma unroll
    for (int r = 0; r < 8; r++) {
        int off = r * 1024 + threadIdx.x * 4;
        int row = off >> 7, colo = off & 127;
        if (nb + row < N_NODES) {
            us4 v = *(const us4*)&h[(nb + row) * HID + colo];
            ht[row][colo + 0] = bf2f(v.x);
            ht[row][colo + 1] = bf2f(v.y);
            ht[row][colo + 2] = bf2f(v.z);
            ht[row][colo + 3] = bf2f(v.w);
        }
    }
    __syncthreads();
    for (int o = threadIdx.x; o < 64 * N_CLASS; o += 256) {
        int n = o / N_CLASS, c = o % N_CLASS;
        if (nb + n < N_NODES) {
            float acc = fcb[c];
            for (int k = 0; k < HID; k++) acc += ht[n][k] * fcW[k * N_CLASS + c];
            out[(nb + n) * N_CLASS + c] = acc;
        }
    }
}

// ---------------------------------------------------------------------------

extern "C" void kernel_launch(void* const* d_in, const int* in_sizes, int n_in,
                              void* d_out, int out_size, void* d_ws, size_t ws_size,
                              hipStream_t stream) {
    const float* x = (const float*)d_in[0];
    const int* ei = (const int*)d_in[1];  // [2][E]
    // d_in[2] = edge_weight (unused by the reference forward)
    const float* Wa = (const float*)d_in[3];   // [3][128][128]
    const float* ba = (const float*)d_in[4];   // [3][128]
    const float* Wb = (const float*)d_in[5];
    const float* bb = (const float*)d_in[6];
    const float* fcW = (const float*)d_in[7];  // [128][10]
    const float* fcb = (const float*)d_in[8];  // [10]
    float* out = (float*)d_out;

    const int* src = ei;
    const int* dst = ei + N_EDGES;

    // workspace carve
    char* w = (char*)d_ws;
    float* zbuf = (float*)w;          w += (size_t)N_PAD * HID * 4;  // fp32 agg out
    unsigned short* hb = (unsigned short*)w; w += (size_t)N_PAD * HID * 2;  // bf16 h
    int* row_ptr = (int*)w;  w += ((size_t)N_NODES + 8) * 4;
    int* cursor = (int*)w;   w += (size_t)N_NODES * 4;
    int* gbase = (int*)w;    w += NR * 4;   // contiguous with cursor (one memset)
    int* col = (int*)w;      w += (size_t)N_EDGES * 4;
    int* bsum = (int*)w;     w += 256 * 4;
    unsigned short* Whp = (unsigned short*)w; w += 6 * 16384 * 2;
    unsigned short* Wlp = (unsigned short*)w; w += 6 * 16384 * 2;
    unsigned* gbuf = (unsigned*)w; w += (size_t)NR * PCAP * 4;

    const int SCAN_BLOCKS = (N_NODES + 1023) / 1024;  // 98

    // ---- weight split/pack + x cast (independent of CSR) ----
    wsplit_k<<<(6 * 16384 + 255) / 256, 256, 0, stream>>>(Wa, Wb, Whp, Wlp);
    cast_k<<<(N_NODES * (HID / 4) + 255) / 256, 256, 0, stream>>>(x, hb);

    // ---- CSR build ----
    hipMemsetAsync(cursor, 0, ((size_t)N_NODES + NR) * 4, stream);  // cursor+gbase
    partition_k<<<P_BLOCKS, 256, 0, stream>>>(src, dst, gbase, gbuf);
    count_k<<<N_EDGES / 256, 256, 0, stream>>>(dst, cursor);
    scan1_k<<<SCAN_BLOCKS, 256, 0, stream>>>(cursor, row_ptr, bsum);
    scan2_k<<<1, 256, 0, stream>>>(bsum, SCAN_BLOCKS);
    scan3_k<<<(N_NODES + 255) / 256, 256, 0, stream>>>(row_ptr, bsum, cursor);
    fill2_k<<<256, 256, 0, stream>>>(gbuf, gbase, cursor, col);

    const int AGG_BLOCKS = (N_NODES * 32 + 255) / 256;  // one half-wave per node
    const int MLP_BLOCKS = (N_NODES + 63) / 64;         // 1563 (ws rows padded)

    // ---- layer 1 ----
    agg_k<<<AGG_BLOCKS, 256, 0, stream>>>(hb, row_ptr, col, zbuf);
    mlp2_k<<<MLP_BLOCKS, 256, 0, stream>>>(zbuf, Whp, Wlp, Whp + 16384, Wlp + 16384,
                                           ba, bb, hb);
    // ---- layer 2 ----
    agg_k<<<AGG_BLOCKS, 256, 0, stream>>>(hb, row_ptr, col, zbuf);
    mlp2_k<<<MLP_BLOCKS, 256, 0, stream>>>(zbuf, Whp + 2 * 16384, Wlp + 2 * 16384,
                                           Whp + 3 * 16384, Wlp + 3 * 16384,
                                           ba + 128, bb + 128, hb);
    // ---- layer 3 ----
    agg_k<<<AGG_BLOCKS, 256, 0, stream>>>(hb, row_ptr, col, zbuf);
    mlp2_k<<<MLP_BLOCKS, 256, 0, stream>>>(zbuf, Whp + 4 * 16384, Wlp + 4 * 16384,
                                           Whp + 5 * 16384, Wlp + 5 * 16384,
                                           ba + 256, bb + 256, hb);
    // ---- final FC ----
    fc_k<<<(N_NODES + 63) / 64, 256, 0, stream>>>(hb, fcW, fcb, out);
}

// Round 6
// 512.052 us; speedup vs baseline: 1.2435x; 1.2435x over previous
//
#include <hip/hip_runtime.h>
#include <hip/hip_bf16.h>
#include <math.h>

#define N_NODES 100000
#define N_PAD 100032   // padded row count for workspace feature buffers
#define N_EDGES 1600000
#define HID 128
#define N_CLASS 10

// edge partition params: 256 dst-ranges of 391 nodes (256*391 = 100096)
#define NR2 256
#define RANGE2 391
#define PCAP2 8192     // per-range packed capacity (expected ~6250, max ~6600)
#define P_BLOCKS 512
#define P_SLICE (N_EDGES / P_BLOCKS)  // 3125

typedef float f32x4 __attribute__((ext_vector_type(4)));
typedef short short8 __attribute__((ext_vector_type(8)));
typedef unsigned short us4 __attribute__((ext_vector_type(4)));

// bf16 helpers (round-to-nearest-even)
__device__ __forceinline__ unsigned short f2bf(float x) {
    unsigned u = __float_as_uint(x);
    unsigned r = u + 0x7FFF + ((u >> 16) & 1);
    return (unsigned short)(r >> 16);
}
__device__ __forceinline__ float bf2f(unsigned short h) {
    return __uint_as_float(((unsigned)h) << 16);
}
__device__ __forceinline__ float elu(float x) {
    return x > 0.f ? x : (expf(x) - 1.f);
}

// ---------------------------------------------------------------------------
// CSR build v3: 256-way partition -> per-range LDS counting sort.
// row_ptr computed inside csort (no global count/scan kernels, no global
// scattered col writes — col is written sequentially in full lines).
// ---------------------------------------------------------------------------

// Pass 1: partition edges into 256 dst-ranges, packed src | (dloc<<17).
__global__ __launch_bounds__(256) void part_k(const int* __restrict__ src,
                                              const int* __restrict__ dst,
                                              int* __restrict__ gcnt,
                                              unsigned* __restrict__ gbuf) {
    __shared__ unsigned stash[P_SLICE];
    __shared__ unsigned char rbuf[P_SLICE];
    __shared__ int hist[NR2], cur[NR2], base[NR2];
    hist[threadIdx.x] = 0;
    cur[threadIdx.x] = 0;
    __syncthreads();
    const int e0 = blockIdx.x * P_SLICE;
    for (int i = threadIdx.x; i < P_SLICE; i += 256) {
        unsigned s = (unsigned)src[e0 + i];
        unsigned d = (unsigned)dst[e0 + i];
        unsigned r = d / RANGE2;            // magic-mul
        unsigned dloc = d - r * RANGE2;     // < 391 (9 bits)
        stash[i] = s | (dloc << 17);
        rbuf[i] = (unsigned char)r;
        atomicAdd(&hist[r], 1);
    }
    __syncthreads();
    base[threadIdx.x] = atomicAdd(&gcnt[threadIdx.x], hist[threadIdx.x]);
    __syncthreads();
    for (int i = threadIdx.x; i < P_SLICE; i += 256) {
        unsigned r = rbuf[i];
        int off = atomicAdd(&cur[r], 1);
        int pos = base[r] + off;
        if (pos < PCAP2) gbuf[(size_t)r * PCAP2 + pos] = stash[i];
    }
}

// exclusive scan of gcnt[256] -> colbase[256]; also row_ptr[N] = E
__global__ void scanc_k(const int* __restrict__ gcnt, int* __restrict__ colbase,
                        int* __restrict__ row_ptr) {
    __shared__ int sh[NR2];
    int v = gcnt[threadIdx.x];
    sh[threadIdx.x] = v;
    __syncthreads();
    for (int off = 1; off < NR2; off <<= 1) {
        int t = (threadIdx.x >= off) ? sh[threadIdx.x - off] : 0;
        __syncthreads();
        sh[threadIdx.x] += t;
        __syncthreads();
    }
    colbase[threadIdx.x] = sh[threadIdx.x] - v;  // exclusive
    if (threadIdx.x == 0) row_ptr[N_NODES] = N_EDGES;
}

// Pass 2: per-range counting sort in LDS; sequential col + row_ptr writes.
__global__ __launch_bounds__(256) void csort_k(const unsigned* __restrict__ gbuf,
                                               const int* __restrict__ gcnt,
                                               const int* __restrict__ colbase,
                                               int* __restrict__ row_ptr,
                                               int* __restrict__ col) {
    __shared__ int sorted[PCAP2];   // 32 KB
    __shared__ int hist[512];       // padded histogram / inclusive scan
    __shared__ int cnt[512];        // original counts
    __shared__ int run[400];        // running cursor (excl start), consumed
    const int q = blockIdx.x;
    const int tid = threadIdx.x;
    const int n2 = gcnt[q];
    const int cb = colbase[q];
    const int node0 = q * RANGE2;
    const unsigned* buf = gbuf + (size_t)q * PCAP2;

    hist[tid] = 0; hist[tid + 256] = 0;
    __syncthreads();
    // histogram over 391 local nodes
    for (int i = tid; i < n2; i += 256)
        atomicAdd(&hist[buf[i] >> 17], 1);
    __syncthreads();
    cnt[tid] = hist[tid];
    cnt[tid + 256] = hist[tid + 256];
    __syncthreads();
    // inclusive scan over 512 entries (Hillis-Steele, 2 elems/thread)
    for (int off = 1; off < 512; off <<= 1) {
        int v0 = (tid >= off) ? hist[tid - off] : 0;
        int v1 = hist[tid + 256 - off];  // tid+256 >= off always (off<=256)
        __syncthreads();
        hist[tid] += v0;
        hist[tid + 256] += v1;
        __syncthreads();
    }
    // exclusive start per bin; write row_ptr
#pragma unroll
    for (int b = 0; b < 2; b++) {
        int i = tid + 256 * b;
        if (i < RANGE2) {
            int excl = hist[i] - cnt[i];
            run[i] = excl;
            int node = node0 + i;
            if (node < N_NODES) row_ptr[node] = cb + excl;
        }
    }
    __syncthreads();
    // scatter into LDS (counting sort)
    for (int i = tid; i < n2; i += 256) {
        unsigned w = buf[i];
        int pos = atomicAdd(&run[w >> 17], 1);
        sorted[pos] = (int)(w & 0x1FFFF);
    }
    __syncthreads();
    // sequential col write (full lines)
    for (int i = tid; i < n2; i += 256) col[cb + i] = sorted[i];
}

// ---------------------------------------------------------------------------
// fp32 -> bf16 cast of x (layer-1 gather source)
// ---------------------------------------------------------------------------
__global__ __launch_bounds__(256) void cast_k(const float* __restrict__ x,
                                              unsigned short* __restrict__ hb) {
    int i = blockIdx.x * blockDim.x + threadIdx.x;  // float4 index
    if (i < N_NODES * (HID / 4)) {
        float4 v = ((const float4*)x)[i];
        us4 o = {f2bf(v.x), f2bf(v.y), f2bf(v.z), f2bf(v.w)};
        ((us4*)hb)[i] = o;
    }
}

// ---------------------------------------------------------------------------
// Weight pre-split + pre-pack into MFMA B-fragment order.
// ---------------------------------------------------------------------------
__global__ void wsplit_k(const float* __restrict__ Wa, const float* __restrict__ Wb,
                         unsigned short* __restrict__ Whp,
                         unsigned short* __restrict__ Wlp) {
    int f = blockIdx.x * blockDim.x + threadIdx.x;
    if (f >= 6 * 16384) return;
    int g = f >> 14;
    int r = f & 16383;
    int j = r & 7;
    int L = (r >> 3) & 63;
    int t = r >> 9;          // kb*8 + nt
    int kb = t >> 3, nt = t & 7;
    int k = kb * 32 + ((L >> 4) & 3) * 8 + j;
    int n = nt * 16 + (L & 15);
    int layer = g >> 1;
    const float* W = (g & 1) ? Wb : Wa;
    float w = W[layer * 16384 + k * 128 + n];
    unsigned short hi = f2bf(w);
    unsigned short lo = f2bf(w - bf2f(hi));
    Whp[f] = hi;
    Wlp[f] = lo;
}

// ---------------------------------------------------------------------------
// Aggregation: one HALF-WAVE (32 lanes) per node, bf16 rows (256B), us4/lane.
// fp32 accumulate. z[n] = h[n] + sum_{s in N(n)} h[s]
// ---------------------------------------------------------------------------
__device__ __forceinline__ float4 us4f(us4 v) {
    float4 o;
    o.x = bf2f(v.x); o.y = bf2f(v.y); o.z = bf2f(v.z); o.w = bf2f(v.w);
    return o;
}

__global__ __launch_bounds__(256) void agg_k(const unsigned short* __restrict__ h,
                                             const int* __restrict__ row_ptr,
                                             const int* __restrict__ col,
                                             float* __restrict__ z) {
    const int half = (blockIdx.x * blockDim.x + threadIdx.x) >> 5;  // node id
    const int lane = threadIdx.x & 31;
    const int halfbase = threadIdx.x & 32;
    if (half >= N_NODES) return;
    const us4* hp = (const us4*)h;  // 32 x us4 per row
    float4 acc = us4f(hp[(size_t)half * 32 + lane]);  // self term, (1+eps)=1
    const int beg = row_ptr[half];
    const int end = row_ptr[half + 1];

    for (int base = beg; base < end; base += 32) {
        const int n = min(32, end - base);
        int myidx = (lane < n) ? col[base + lane] : 0;
        int j = 0;
        for (; j + 4 <= n; j += 4) {
            int i0 = __shfl(myidx, halfbase + j + 0, 64);
            int i1 = __shfl(myidx, halfbase + j + 1, 64);
            int i2 = __shfl(myidx, halfbase + j + 2, 64);
            int i3 = __shfl(myidx, halfbase + j + 3, 64);
            float4 v0 = us4f(hp[(size_t)i0 * 32 + lane]);
            float4 v1 = us4f(hp[(size_t)i1 * 32 + lane]);
            float4 v2 = us4f(hp[(size_t)i2 * 32 + lane]);
            float4 v3 = us4f(hp[(size_t)i3 * 32 + lane]);
            acc.x += v0.x; acc.y += v0.y; acc.z += v0.z; acc.w += v0.w;
            acc.x += v1.x; acc.y += v1.y; acc.z += v1.z; acc.w += v1.w;
            acc.x += v2.x; acc.y += v2.y; acc.z += v2.z; acc.w += v2.w;
            acc.x += v3.x; acc.y += v3.y; acc.z += v3.z; acc.w += v3.w;
        }
        for (; j < n; j++) {
            int i0 = __shfl(myidx, halfbase + j, 64);
            float4 v0 = us4f(hp[(size_t)i0 * 32 + lane]);
            acc.x += v0.x; acc.y += v0.y; acc.z += v0.z; acc.w += v0.w;
        }
    }
    ((float4*)z)[(size_t)half * 32 + lane] = acc;  // fp32 out, 32 float4/row
}

// ---------------------------------------------------------------------------
// MFMA MLP: h_out(bf16) = ELU(ELU(z@Wa + ba)@Wb + bb), split-bf16 x3 terms.
// W-hi and W-lo both read from global (L2-broadcast, 32 KB each); LDS only
// holds A hi/lo (32 KB) -> 4 blocks/CU.
// ---------------------------------------------------------------------------
__device__ __forceinline__ void gemm_phase(
    const unsigned short* Aph_, const unsigned short* Apl_,
    const unsigned short* __restrict__ Whi_g,
    const unsigned short* __restrict__ Wlo_g,
    const float* __restrict__ bias, int tid, f32x4 acc[2][4]) {
    const int L = tid & 63;
    const int w = tid >> 6;
    const int mt0 = (w >> 1) * 2;
    const int nt0 = (w & 1) * 4;
    const int lan15 = L & 15;
#pragma unroll
    for (int n = 0; n < 4; n++) {
        float b = bias[(nt0 + n) * 16 + lan15];
        f32x4 bv = {b, b, b, b};
        acc[0][n] = bv;
        acc[1][n] = bv;
    }
#pragma unroll
    for (int kb = 0; kb < 4; kb++) {
        short8 ah0 = *(const short8*)&Aph_[(((mt0 + 0) * 4 + kb) * 64 + L) * 8];
        short8 ah1 = *(const short8*)&Aph_[(((mt0 + 1) * 4 + kb) * 64 + L) * 8];
        short8 al0 = *(const short8*)&Apl_[(((mt0 + 0) * 4 + kb) * 64 + L) * 8];
        short8 al1 = *(const short8*)&Apl_[(((mt0 + 1) * 4 + kb) * 64 + L) * 8];
#pragma unroll
        for (int n = 0; n < 4; n++) {
            int widx = ((kb * 8 + nt0 + n) * 64 + L) * 8;
            short8 bh = *(const short8*)&Whi_g[widx];
            short8 bl = *(const short8*)&Wlo_g[widx];
            acc[0][n] = __builtin_amdgcn_mfma_f32_16x16x32_bf16(ah0, bh, acc[0][n], 0, 0, 0);
            acc[1][n] = __builtin_amdgcn_mfma_f32_16x16x32_bf16(ah1, bh, acc[1][n], 0, 0, 0);
            acc[0][n] = __builtin_amdgcn_mfma_f32_16x16x32_bf16(al0, bh, acc[0][n], 0, 0, 0);
            acc[1][n] = __builtin_amdgcn_mfma_f32_16x16x32_bf16(al1, bh, acc[1][n], 0, 0, 0);
            acc[0][n] = __builtin_amdgcn_mfma_f32_16x16x32_bf16(ah0, bl, acc[0][n], 0, 0, 0);
            acc[1][n] = __builtin_amdgcn_mfma_f32_16x16x32_bf16(ah1, bl, acc[1][n], 0, 0, 0);
        }
    }
}

__global__ __launch_bounds__(256) void mlp2_k(
    const float* __restrict__ zin,
    const unsigned short* __restrict__ Wahp, const unsigned short* __restrict__ Walp,
    const unsigned short* __restrict__ Wbhp, const unsigned short* __restrict__ Wblp,
    const float* __restrict__ ba, const float* __restrict__ bb,
    unsigned short* __restrict__ hout) {
    __shared__ unsigned short Aph[8192];   // 16 KB: packed A hi
    __shared__ unsigned short Apl[8192];   // 16 KB: packed A lo

    const int tid = threadIdx.x;
    const int L = tid & 63;
    const int w = tid >> 6;
    const int mt0 = (w >> 1) * 2;
    const int nt0 = (w & 1) * 4;
    const int lan15 = L & 15;
    const int quad = L >> 4;
    const size_t node_base = (size_t)blockIdx.x * 64;

    // ---- phase A: load z tile, split to bf16 hi/lo, pack to A-frag layout ----
    {
        const float4* zin4 = (const float4*)(zin + node_base * HID);
#pragma unroll
        for (int r = 0; r < 8; r++) {
            int f = tid + 256 * r;          // [0, 2048)
            int m = f >> 5;
            int k0 = (f & 31) * 4;
            float4 zv = zin4[f];
            int kb = k0 >> 5;
            int q = (k0 & 31) >> 3;
            int j0 = k0 & 7;                 // 0 or 4
            int idx = (((m >> 4) * 4 + kb) * 64 + ((m & 15) + 16 * q)) * 8 + j0;
            unsigned short hx = f2bf(zv.x), hy = f2bf(zv.y),
                           hz = f2bf(zv.z), hw = f2bf(zv.w);
            us4 h4 = {hx, hy, hz, hw};
            us4 l4 = {f2bf(zv.x - bf2f(hx)), f2bf(zv.y - bf2f(hy)),
                      f2bf(zv.z - bf2f(hz)), f2bf(zv.w - bf2f(hw))};
            *(us4*)&Aph[idx] = h4;
            *(us4*)&Apl[idx] = l4;
        }
    }
    __syncthreads();

    // ---- GEMM1: t = ELU(z @ Wa + ba) ----
    {
        f32x4 acc[2][4];
        gemm_phase(Aph, Apl, Wahp, Walp, ba, tid, acc);
        __syncthreads();  // all waves done reading A frags
#pragma unroll
        for (int i = 0; i < 2; i++) {
#pragma unroll
            for (int n = 0; n < 4; n++) {
                int kdim = (nt0 + n) * 16 + lan15;
                int kb2 = kdim >> 5;
                int q2 = (kdim & 31) >> 3;
                int j2 = kdim & 7;
#pragma unroll
                for (int r = 0; r < 4; r++) {
                    float v = elu(acc[i][n][r]);
                    int mrow = quad * 4 + r;
                    unsigned short hi = f2bf(v);
                    unsigned short lo = f2bf(v - bf2f(hi));
                    int idx = (((mt0 + i) * 4 + kb2) * 64 + (mrow + 16 * q2)) * 8 + j2;
                    Aph[idx] = hi;
                    Apl[idx] = lo;
                }
            }
        }
    }
    __syncthreads();

    // ---- GEMM2: h = ELU(t @ Wb + bb), bf16 store ----
    {
        f32x4 acc[2][4];
        gemm_phase(Aph, Apl, Wbhp, Wblp, bb, tid, acc);
#pragma unroll
        for (int i = 0; i < 2; i++) {
#pragma unroll
            for (int n = 0; n < 4; n++) {
                int ncol = (nt0 + n) * 16 + lan15;
#pragma unroll
                for (int r = 0; r < 4; r++) {
                    int mrow = (mt0 + i) * 16 + quad * 4 + r;
                    hout[(node_base + mrow) * HID + ncol] = f2bf(elu(acc[i][n][r]));
                }
            }
        }
    }
}

// ---------------------------------------------------------------------------
// Final FC: out = h(bf16) @ fcW + fcb   [100k x 10]
// ---------------------------------------------------------------------------
__global__ __launch_bounds__(256) void fc_k(const unsigned short* __restrict__ h,
                                            const float* __restrict__ fcW,
                                            const float* __restrict__ fcb,
                                            float* __restrict__ out) {
    __shared__ float ht[64][HID + 4];
    size_t nb = (size_t)blockIdx.x * 64;
#pragma unroll
    for (int r = 0; r < 8; r++) {
        int off = r * 1024 + threadIdx.x * 4;
        int row = off >> 7, colo = off & 127;
        if (nb + row < N_NODES) {
            us4 v = *(const us4*)&h[(nb + row) * HID + colo];
            ht[row][colo + 0] = bf2f(v.x);
            ht[row][colo + 1] = bf2f(v.y);
            ht[row][colo + 2] = bf2f(v.z);
            ht[row][colo + 3] = bf2f(v.w);
        }
    }
    __syncthreads();
    for (int o = threadIdx.x; o < 64 * N_CLASS; o += 256) {
        int n = o / N_CLASS, c = o % N_CLASS;
        if (nb + n < N_NODES) {
            float acc = fcb[c];
            for (int k = 0; k < HID; k++) acc += ht[n][k] * fcW[k * N_CLASS + c];
            out[(nb + n) * N_CLASS + c] = acc;
        }
    }
}

// ---------------------------------------------------------------------------

extern "C" void kernel_launch(void* const* d_in, const int* in_sizes, int n_in,
                              void* d_out, int out_size, void* d_ws, size_t ws_size,
                              hipStream_t stream) {
    const float* x = (const float*)d_in[0];
    const int* ei = (const int*)d_in[1];  // [2][E]
    // d_in[2] = edge_weight (unused by the reference forward)
    const float* Wa = (const float*)d_in[3];   // [3][128][128]
    const float* ba = (const float*)d_in[4];   // [3][128]
    const float* Wb = (const float*)d_in[5];
    const float* bb = (const float*)d_in[6];
    const float* fcW = (const float*)d_in[7];  // [128][10]
    const float* fcb = (const float*)d_in[8];  // [10]
    float* out = (float*)d_out;

    const int* src = ei;
    const int* dst = ei + N_EDGES;

    // workspace carve
    char* w = (char*)d_ws;
    float* zbuf = (float*)w;          w += (size_t)N_PAD * HID * 4;  // fp32 agg out
    unsigned short* hb = (unsigned short*)w; w += (size_t)N_PAD * HID * 2;  // bf16 h
    int* row_ptr = (int*)w;  w += ((size_t)N_NODES + 8) * 4;
    int* gcnt = (int*)w;     w += NR2 * 4;
    int* colbase = (int*)w;  w += NR2 * 4;
    int* col = (int*)w;      w += (size_t)N_EDGES * 4;
    unsigned short* Whp = (unsigned short*)w; w += 6 * 16384 * 2;
    unsigned short* Wlp = (unsigned short*)w; w += 6 * 16384 * 2;
    unsigned* gbuf = (unsigned*)w; w += (size_t)NR2 * PCAP2 * 4;  // 8 MB

    // ---- weight split/pack + x cast (independent of CSR) ----
    wsplit_k<<<(6 * 16384 + 255) / 256, 256, 0, stream>>>(Wa, Wb, Whp, Wlp);
    cast_k<<<(N_NODES * (HID / 4) + 255) / 256, 256, 0, stream>>>(x, hb);

    // ---- CSR build v3 ----
    hipMemsetAsync(gcnt, 0, NR2 * 4, stream);
    part_k<<<P_BLOCKS, 256, 0, stream>>>(src, dst, gcnt, gbuf);
    scanc_k<<<1, 256, 0, stream>>>(gcnt, colbase, row_ptr);
    csort_k<<<NR2, 256, 0, stream>>>(gbuf, gcnt, colbase, row_ptr, col);

    const int AGG_BLOCKS = (N_NODES * 32 + 255) / 256;  // one half-wave per node
    const int MLP_BLOCKS = (N_NODES + 63) / 64;         // 1563 (ws rows padded)

    // ---- layer 1 ----
    agg_k<<<AGG_BLOCKS, 256, 0, stream>>>(hb, row_ptr, col, zbuf);
    mlp2_k<<<MLP_BLOCKS, 256, 0, stream>>>(zbuf, Whp, Wlp, Whp + 16384, Wlp + 16384,
                                           ba, bb, hb);
    // ---- layer 2 ----
    agg_k<<<AGG_BLOCKS, 256, 0, stream>>>(hb, row_ptr, col, zbuf);
    mlp2_k<<<MLP_BLOCKS, 256, 0, stream>>>(zbuf, Whp + 2 * 16384, Wlp + 2 * 16384,
                                           Whp + 3 * 16384, Wlp + 3 * 16384,
                                           ba + 128, bb + 128, hb);
    // ---- layer 3 ----
    agg_k<<<AGG_BLOCKS, 256, 0, stream>>>(hb, row_ptr, col, zbuf);
    mlp2_k<<<MLP_BLOCKS, 256, 0, stream>>>(zbuf, Whp + 4 * 16384, Wlp + 4 * 16384,
                                           Whp + 5 * 16384, Wlp + 5 * 16384,
                                           ba + 256, bb + 256, hb);
    // ---- final FC ----
    fc_k<<<(N_NODES + 63) / 64, 256, 0, stream>>>(hb, fcW, fcb, out);
}

// Round 7
// 455.187 us; speedup vs baseline: 1.3988x; 1.1249x over previous
//
#include <hip/hip_runtime.h>
#include <hip/hip_bf16.h>
#include <math.h>

#define N_NODES 100000
#define N_PAD 100032   // padded row count for workspace feature buffers
#define N_EDGES 1600000
#define HID 128
#define N_CLASS 10

// edge partition params: 256 dst-ranges of 391 nodes (256*391 = 100096)
#define NR2 256
#define RANGE2 391
#define PCAP2 8192     // per-range packed capacity (expected ~6250, max ~6600)
#define P_BLOCKS 512
#define P_SLICE (N_EDGES / P_BLOCKS)  // 3125

typedef float f32x4 __attribute__((ext_vector_type(4)));
typedef short short8 __attribute__((ext_vector_type(8)));
typedef unsigned short us4 __attribute__((ext_vector_type(4)));

// bf16 helpers (round-to-nearest-even)
__device__ __forceinline__ unsigned short f2bf(float x) {
    unsigned u = __float_as_uint(x);
    unsigned r = u + 0x7FFF + ((u >> 16) & 1);
    return (unsigned short)(r >> 16);
}
__device__ __forceinline__ float bf2f(unsigned short h) {
    return __uint_as_float(((unsigned)h) << 16);
}
__device__ __forceinline__ float elu(float x) {
    return x > 0.f ? x : (expf(x) - 1.f);
}

// ---------------------------------------------------------------------------
// CSR build v3: 256-way partition -> per-range LDS counting sort.
// ---------------------------------------------------------------------------

__global__ __launch_bounds__(256) void part_k(const int* __restrict__ src,
                                              const int* __restrict__ dst,
                                              int* __restrict__ gcnt,
                                              unsigned* __restrict__ gbuf) {
    __shared__ unsigned stash[P_SLICE];
    __shared__ unsigned char rbuf[P_SLICE];
    __shared__ int hist[NR2], cur[NR2], base[NR2];
    hist[threadIdx.x] = 0;
    cur[threadIdx.x] = 0;
    __syncthreads();
    const int e0 = blockIdx.x * P_SLICE;
    for (int i = threadIdx.x; i < P_SLICE; i += 256) {
        unsigned s = (unsigned)src[e0 + i];
        unsigned d = (unsigned)dst[e0 + i];
        unsigned r = d / RANGE2;            // magic-mul
        unsigned dloc = d - r * RANGE2;     // < 391 (9 bits)
        stash[i] = s | (dloc << 17);
        rbuf[i] = (unsigned char)r;
        atomicAdd(&hist[r], 1);
    }
    __syncthreads();
    base[threadIdx.x] = atomicAdd(&gcnt[threadIdx.x], hist[threadIdx.x]);
    __syncthreads();
    for (int i = threadIdx.x; i < P_SLICE; i += 256) {
        unsigned r = rbuf[i];
        int off = atomicAdd(&cur[r], 1);
        int pos = base[r] + off;
        if (pos < PCAP2) gbuf[(size_t)r * PCAP2 + pos] = stash[i];
    }
}

__global__ void scanc_k(const int* __restrict__ gcnt, int* __restrict__ colbase,
                        int* __restrict__ row_ptr) {
    __shared__ int sh[NR2];
    int v = gcnt[threadIdx.x];
    sh[threadIdx.x] = v;
    __syncthreads();
    for (int off = 1; off < NR2; off <<= 1) {
        int t = (threadIdx.x >= off) ? sh[threadIdx.x - off] : 0;
        __syncthreads();
        sh[threadIdx.x] += t;
        __syncthreads();
    }
    colbase[threadIdx.x] = sh[threadIdx.x] - v;  // exclusive
    if (threadIdx.x == 0) row_ptr[N_NODES] = N_EDGES;
}

__global__ __launch_bounds__(256) void csort_k(const unsigned* __restrict__ gbuf,
                                               const int* __restrict__ gcnt,
                                               const int* __restrict__ colbase,
                                               int* __restrict__ row_ptr,
                                               int* __restrict__ col) {
    __shared__ int sorted[PCAP2];   // 32 KB
    __shared__ int hist[512];
    __shared__ int cnt[512];
    __shared__ int run[400];
    const int q = blockIdx.x;
    const int tid = threadIdx.x;
    const int n2 = gcnt[q];
    const int cb = colbase[q];
    const int node0 = q * RANGE2;
    const unsigned* buf = gbuf + (size_t)q * PCAP2;

    hist[tid] = 0; hist[tid + 256] = 0;
    __syncthreads();
    for (int i = tid; i < n2; i += 256)
        atomicAdd(&hist[buf[i] >> 17], 1);
    __syncthreads();
    cnt[tid] = hist[tid];
    cnt[tid + 256] = hist[tid + 256];
    __syncthreads();
    for (int off = 1; off < 512; off <<= 1) {
        int v0 = (tid >= off) ? hist[tid - off] : 0;
        int v1 = hist[tid + 256 - off];
        __syncthreads();
        hist[tid] += v0;
        hist[tid + 256] += v1;
        __syncthreads();
    }
#pragma unroll
    for (int b = 0; b < 2; b++) {
        int i = tid + 256 * b;
        if (i < RANGE2) {
            int excl = hist[i] - cnt[i];
            run[i] = excl;
            int node = node0 + i;
            if (node < N_NODES) row_ptr[node] = cb + excl;
        }
    }
    __syncthreads();
    for (int i = tid; i < n2; i += 256) {
        unsigned w = buf[i];
        int pos = atomicAdd(&run[w >> 17], 1);
        sorted[pos] = (int)(w & 0x1FFFF);
    }
    __syncthreads();
    for (int i = tid; i < n2; i += 256) col[cb + i] = sorted[i];
}

// ---------------------------------------------------------------------------
// fp32 -> bf16 cast of x (layer-1 gather source)
// ---------------------------------------------------------------------------
__global__ __launch_bounds__(256) void cast_k(const float* __restrict__ x,
                                              unsigned short* __restrict__ hb) {
    int i = blockIdx.x * blockDim.x + threadIdx.x;  // float4 index
    if (i < N_NODES * (HID / 4)) {
        float4 v = ((const float4*)x)[i];
        us4 o = {f2bf(v.x), f2bf(v.y), f2bf(v.z), f2bf(v.w)};
        ((us4*)hb)[i] = o;
    }
}

// ---------------------------------------------------------------------------
// Weight pre-split + pre-pack into MFMA B-fragment order.
// ---------------------------------------------------------------------------
__global__ void wsplit_k(const float* __restrict__ Wa, const float* __restrict__ Wb,
                         unsigned short* __restrict__ Whp,
                         unsigned short* __restrict__ Wlp) {
    int f = blockIdx.x * blockDim.x + threadIdx.x;
    if (f >= 6 * 16384) return;
    int g = f >> 14;
    int r = f & 16383;
    int j = r & 7;
    int L = (r >> 3) & 63;
    int t = r >> 9;          // kb*8 + nt
    int kb = t >> 3, nt = t & 7;
    int k = kb * 32 + ((L >> 4) & 3) * 8 + j;
    int n = nt * 16 + (L & 15);
    int layer = g >> 1;
    const float* W = (g & 1) ? Wb : Wa;
    float w = W[layer * 16384 + k * 128 + n];
    unsigned short hi = f2bf(w);
    unsigned short lo = f2bf(w - bf2f(hi));
    Whp[f] = hi;
    Wlp[f] = lo;
}

// fcW [128][10] -> B-frag layout, N padded to 16. idx = (kb*64+L)*8+j,
// k = kb*32 + (L>>4)*8 + j, n = L&15 (0 for n>=10).
__global__ void fcsplit_k(const float* __restrict__ fcW,
                          unsigned short* __restrict__ fcWph,
                          unsigned short* __restrict__ fcWpl) {
    int f = blockIdx.x * blockDim.x + threadIdx.x;
    if (f >= 2048) return;
    int j = f & 7;
    int L = (f >> 3) & 63;
    int kb = f >> 9;
    int k = kb * 32 + ((L >> 4) & 3) * 8 + j;
    int n = L & 15;
    float w = (n < N_CLASS) ? fcW[k * N_CLASS + n] : 0.f;
    unsigned short hi = f2bf(w);
    unsigned short lo = f2bf(w - bf2f(hi));
    fcWph[f] = hi;
    fcWpl[f] = lo;
}

// ---------------------------------------------------------------------------
// Aggregation: one HALF-WAVE (32 lanes) per node, bf16 rows (256B), us4/lane.
// ---------------------------------------------------------------------------
__device__ __forceinline__ float4 us4f(us4 v) {
    float4 o;
    o.x = bf2f(v.x); o.y = bf2f(v.y); o.z = bf2f(v.z); o.w = bf2f(v.w);
    return o;
}

__global__ __launch_bounds__(256) void agg_k(const unsigned short* __restrict__ h,
                                             const int* __restrict__ row_ptr,
                                             const int* __restrict__ col,
                                             float* __restrict__ z) {
    const int half = (blockIdx.x * blockDim.x + threadIdx.x) >> 5;  // node id
    const int lane = threadIdx.x & 31;
    const int halfbase = threadIdx.x & 32;
    if (half >= N_NODES) return;
    const us4* hp = (const us4*)h;  // 32 x us4 per row
    float4 acc = us4f(hp[(size_t)half * 32 + lane]);  // self term, (1+eps)=1
    const int beg = row_ptr[half];
    const int end = row_ptr[half + 1];

    for (int base = beg; base < end; base += 32) {
        const int n = min(32, end - base);
        int myidx = (lane < n) ? col[base + lane] : 0;
        int j = 0;
        for (; j + 4 <= n; j += 4) {
            int i0 = __shfl(myidx, halfbase + j + 0, 64);
            int i1 = __shfl(myidx, halfbase + j + 1, 64);
            int i2 = __shfl(myidx, halfbase + j + 2, 64);
            int i3 = __shfl(myidx, halfbase + j + 3, 64);
            float4 v0 = us4f(hp[(size_t)i0 * 32 + lane]);
            float4 v1 = us4f(hp[(size_t)i1 * 32 + lane]);
            float4 v2 = us4f(hp[(size_t)i2 * 32 + lane]);
            float4 v3 = us4f(hp[(size_t)i3 * 32 + lane]);
            acc.x += v0.x; acc.y += v0.y; acc.z += v0.z; acc.w += v0.w;
            acc.x += v1.x; acc.y += v1.y; acc.z += v1.z; acc.w += v1.w;
            acc.x += v2.x; acc.y += v2.y; acc.z += v2.z; acc.w += v2.w;
            acc.x += v3.x; acc.y += v3.y; acc.z += v3.z; acc.w += v3.w;
        }
        for (; j < n; j++) {
            int i0 = __shfl(myidx, halfbase + j, 64);
            float4 v0 = us4f(hp[(size_t)i0 * 32 + lane]);
            acc.x += v0.x; acc.y += v0.y; acc.z += v0.z; acc.w += v0.w;
        }
    }
    ((float4*)z)[(size_t)half * 32 + lane] = acc;  // fp32 out, 32 float4/row
}

// ---------------------------------------------------------------------------
// MFMA MLP: h_out(bf16) = ELU(ELU(z@Wa + ba)@Wb + bb), split-bf16 x3 terms.
// mlp3_k additionally fuses the final FC (h @ fcW + fcb) and skips hout.
// ---------------------------------------------------------------------------
__device__ __forceinline__ void gemm_phase(
    const unsigned short* Aph_, const unsigned short* Apl_,
    const unsigned short* __restrict__ Whi_g,
    const unsigned short* __restrict__ Wlo_g,
    const float* __restrict__ bias, int tid, f32x4 acc[2][4]) {
    const int L = tid & 63;
    const int w = tid >> 6;
    const int mt0 = (w >> 1) * 2;
    const int nt0 = (w & 1) * 4;
    const int lan15 = L & 15;
#pragma unroll
    for (int n = 0; n < 4; n++) {
        float b = bias[(nt0 + n) * 16 + lan15];
        f32x4 bv = {b, b, b, b};
        acc[0][n] = bv;
        acc[1][n] = bv;
    }
#pragma unroll
    for (int kb = 0; kb < 4; kb++) {
        short8 ah0 = *(const short8*)&Aph_[(((mt0 + 0) * 4 + kb) * 64 + L) * 8];
        short8 ah1 = *(const short8*)&Aph_[(((mt0 + 1) * 4 + kb) * 64 + L) * 8];
        short8 al0 = *(const short8*)&Apl_[(((mt0 + 0) * 4 + kb) * 64 + L) * 8];
        short8 al1 = *(const short8*)&Apl_[(((mt0 + 1) * 4 + kb) * 64 + L) * 8];
#pragma unroll
        for (int n = 0; n < 4; n++) {
            int widx = ((kb * 8 + nt0 + n) * 64 + L) * 8;
            short8 bh = *(const short8*)&Whi_g[widx];
            short8 bl = *(const short8*)&Wlo_g[widx];
            acc[0][n] = __builtin_amdgcn_mfma_f32_16x16x32_bf16(ah0, bh, acc[0][n], 0, 0, 0);
            acc[1][n] = __builtin_amdgcn_mfma_f32_16x16x32_bf16(ah1, bh, acc[1][n], 0, 0, 0);
            acc[0][n] = __builtin_amdgcn_mfma_f32_16x16x32_bf16(al0, bh, acc[0][n], 0, 0, 0);
            acc[1][n] = __builtin_amdgcn_mfma_f32_16x16x32_bf16(al1, bh, acc[1][n], 0, 0, 0);
            acc[0][n] = __builtin_amdgcn_mfma_f32_16x16x32_bf16(ah0, bl, acc[0][n], 0, 0, 0);
            acc[1][n] = __builtin_amdgcn_mfma_f32_16x16x32_bf16(ah1, bl, acc[1][n], 0, 0, 0);
        }
    }
}

// shared body: FC==0 -> store bf16 h to hout; FC==1 -> fused final FC to out
template <int FC>
__device__ __forceinline__ void mlp_body(
    const float* __restrict__ zin,
    const unsigned short* __restrict__ Wahp, const unsigned short* __restrict__ Walp,
    const unsigned short* __restrict__ Wbhp, const unsigned short* __restrict__ Wblp,
    const float* __restrict__ ba, const float* __restrict__ bb,
    unsigned short* __restrict__ hout,
    const unsigned short* __restrict__ fcWph, const unsigned short* __restrict__ fcWpl,
    const float* __restrict__ fcb, float* __restrict__ out) {
    __shared__ unsigned short Aph[8192];   // 16 KB: packed A hi
    __shared__ unsigned short Apl[8192];   // 16 KB: packed A lo

    const int tid = threadIdx.x;
    const int L = tid & 63;
    const int w = tid >> 6;
    const int mt0 = (w >> 1) * 2;
    const int nt0 = (w & 1) * 4;
    const int lan15 = L & 15;
    const int quad = L >> 4;
    const size_t node_base = (size_t)blockIdx.x * 64;

    // ---- phase A: load z tile, split to bf16 hi/lo, pack to A-frag layout ----
    {
        const float4* zin4 = (const float4*)(zin + node_base * HID);
#pragma unroll
        for (int r = 0; r < 8; r++) {
            int f = tid + 256 * r;          // [0, 2048)
            int m = f >> 5;
            int k0 = (f & 31) * 4;
            float4 zv = zin4[f];
            int kb = k0 >> 5;
            int q = (k0 & 31) >> 3;
            int j0 = k0 & 7;                 // 0 or 4
            int idx = (((m >> 4) * 4 + kb) * 64 + ((m & 15) + 16 * q)) * 8 + j0;
            unsigned short hx = f2bf(zv.x), hy = f2bf(zv.y),
                           hz = f2bf(zv.z), hw = f2bf(zv.w);
            us4 h4 = {hx, hy, hz, hw};
            us4 l4 = {f2bf(zv.x - bf2f(hx)), f2bf(zv.y - bf2f(hy)),
                      f2bf(zv.z - bf2f(hz)), f2bf(zv.w - bf2f(hw))};
            *(us4*)&Aph[idx] = h4;
            *(us4*)&Apl[idx] = l4;
        }
    }
    __syncthreads();

    // ---- GEMM1: t = ELU(z @ Wa + ba) ----
    {
        f32x4 acc[2][4];
        gemm_phase(Aph, Apl, Wahp, Walp, ba, tid, acc);
        __syncthreads();
#pragma unroll
        for (int i = 0; i < 2; i++) {
#pragma unroll
            for (int n = 0; n < 4; n++) {
                int kdim = (nt0 + n) * 16 + lan15;
                int kb2 = kdim >> 5;
                int q2 = (kdim & 31) >> 3;
                int j2 = kdim & 7;
#pragma unroll
                for (int r = 0; r < 4; r++) {
                    float v = elu(acc[i][n][r]);
                    int mrow = quad * 4 + r;
                    unsigned short hi = f2bf(v);
                    unsigned short lo = f2bf(v - bf2f(hi));
                    int idx = (((mt0 + i) * 4 + kb2) * 64 + (mrow + 16 * q2)) * 8 + j2;
                    Aph[idx] = hi;
                    Apl[idx] = lo;
                }
            }
        }
    }
    __syncthreads();

    // ---- GEMM2: h = ELU(t @ Wb + bb) ----
    {
        f32x4 acc[2][4];
        gemm_phase(Aph, Apl, Wbhp, Wblp, bb, tid, acc);
        if (FC == 0) {
#pragma unroll
            for (int i = 0; i < 2; i++) {
#pragma unroll
                for (int n = 0; n < 4; n++) {
                    int ncol = (nt0 + n) * 16 + lan15;
#pragma unroll
                    for (int r = 0; r < 4; r++) {
                        int mrow = (mt0 + i) * 16 + quad * 4 + r;
                        hout[(node_base + mrow) * HID + ncol] = f2bf(elu(acc[i][n][r]));
                    }
                }
            }
        } else {
            // repack h-hi (bf16, identical rounding to the stored-h path)
            // into A-frag layout for the fused FC GEMM
            __syncthreads();  // all waves done reading GEMM2 A frags
#pragma unroll
            for (int i = 0; i < 2; i++) {
#pragma unroll
                for (int n = 0; n < 4; n++) {
                    int kdim = (nt0 + n) * 16 + lan15;
                    int kb2 = kdim >> 5;
                    int q2 = (kdim & 31) >> 3;
                    int j2 = kdim & 7;
#pragma unroll
                    for (int r = 0; r < 4; r++) {
                        float v = elu(acc[i][n][r]);
                        int mrow = quad * 4 + r;
                        int idx = (((mt0 + i) * 4 + kb2) * 64 + (mrow + 16 * q2)) * 8 + j2;
                        Aph[idx] = f2bf(v);
                    }
                }
            }
            __syncthreads();
            // FC: waves 0 and 2 each handle their 2 M-tiles vs N-tile 0
            if ((w & 1) == 0) {
#pragma unroll
                for (int i = 0; i < 2; i++) {
                    int mt = mt0 + i;
                    float b = (lan15 < N_CLASS) ? fcb[lan15] : 0.f;
                    f32x4 acc2 = {b, b, b, b};
#pragma unroll
                    for (int kb = 0; kb < 4; kb++) {
                        short8 a = *(const short8*)&Aph[((mt * 4 + kb) * 64 + L) * 8];
                        short8 bh = *(const short8*)&fcWph[(kb * 64 + L) * 8];
                        short8 bl = *(const short8*)&fcWpl[(kb * 64 + L) * 8];
                        acc2 = __builtin_amdgcn_mfma_f32_16x16x32_bf16(a, bh, acc2, 0, 0, 0);
                        acc2 = __builtin_amdgcn_mfma_f32_16x16x32_bf16(a, bl, acc2, 0, 0, 0);
                    }
#pragma unroll
                    for (int r = 0; r < 4; r++) {
                        size_t node = node_base + mt * 16 + quad * 4 + r;
                        if (node < N_NODES && lan15 < N_CLASS)
                            out[node * N_CLASS + lan15] = acc2[r];
                    }
                }
            }
        }
    }
}

__global__ __launch_bounds__(256) void mlp2_k(
    const float* __restrict__ zin,
    const unsigned short* __restrict__ Wahp, const unsigned short* __restrict__ Walp,
    const unsigned short* __restrict__ Wbhp, const unsigned short* __restrict__ Wblp,
    const float* __restrict__ ba, const float* __restrict__ bb,
    unsigned short* __restrict__ hout) {
    mlp_body<0>(zin, Wahp, Walp, Wbhp, Wblp, ba, bb, hout,
                nullptr, nullptr, nullptr, nullptr);
}

__global__ __launch_bounds__(256) void mlp3_k(
    const float* __restrict__ zin,
    const unsigned short* __restrict__ Wahp, const unsigned short* __restrict__ Walp,
    const unsigned short* __restrict__ Wbhp, const unsigned short* __restrict__ Wblp,
    const float* __restrict__ ba, const float* __restrict__ bb,
    const unsigned short* __restrict__ fcWph, const unsigned short* __restrict__ fcWpl,
    const float* __restrict__ fcb, float* __restrict__ out) {
    mlp_body<1>(zin, Wahp, Walp, Wbhp, Wblp, ba, bb, nullptr,
                fcWph, fcWpl, fcb, out);
}

// ---------------------------------------------------------------------------

extern "C" void kernel_launch(void* const* d_in, const int* in_sizes, int n_in,
                              void* d_out, int out_size, void* d_ws, size_t ws_size,
                              hipStream_t stream) {
    const float* x = (const float*)d_in[0];
    const int* ei = (const int*)d_in[1];  // [2][E]
    // d_in[2] = edge_weight (unused by the reference forward)
    const float* Wa = (const float*)d_in[3];   // [3][128][128]
    const float* ba = (const float*)d_in[4];   // [3][128]
    const float* Wb = (const float*)d_in[5];
    const float* bb = (const float*)d_in[6];
    const float* fcW = (const float*)d_in[7];  // [128][10]
    const float* fcb = (const float*)d_in[8];  // [10]
    float* out = (float*)d_out;

    const int* src = ei;
    const int* dst = ei + N_EDGES;

    // workspace carve
    char* w = (char*)d_ws;
    float* zbuf = (float*)w;          w += (size_t)N_PAD * HID * 4;  // fp32 agg out
    unsigned short* hb = (unsigned short*)w; w += (size_t)N_PAD * HID * 2;  // bf16 h
    int* row_ptr = (int*)w;  w += ((size_t)N_NODES + 8) * 4;
    int* gcnt = (int*)w;     w += NR2 * 4;
    int* colbase = (int*)w;  w += NR2 * 4;
    int* col = (int*)w;      w += (size_t)N_EDGES * 4;
    unsigned short* Whp = (unsigned short*)w; w += 6 * 16384 * 2;
    unsigned short* Wlp = (unsigned short*)w; w += 6 * 16384 * 2;
    unsigned short* fcWph = (unsigned short*)w; w += 2048 * 2;
    unsigned short* fcWpl = (unsigned short*)w; w += 2048 * 2;
    unsigned* gbuf = (unsigned*)w; w += (size_t)NR2 * PCAP2 * 4;  // 8 MB

    // ---- weight split/pack + x cast (independent of CSR) ----
    wsplit_k<<<(6 * 16384 + 255) / 256, 256, 0, stream>>>(Wa, Wb, Whp, Wlp);
    fcsplit_k<<<8, 256, 0, stream>>>(fcW, fcWph, fcWpl);
    cast_k<<<(N_NODES * (HID / 4) + 255) / 256, 256, 0, stream>>>(x, hb);

    // ---- CSR build v3 ----
    hipMemsetAsync(gcnt, 0, NR2 * 4, stream);
    part_k<<<P_BLOCKS, 256, 0, stream>>>(src, dst, gcnt, gbuf);
    scanc_k<<<1, 256, 0, stream>>>(gcnt, colbase, row_ptr);
    csort_k<<<NR2, 256, 0, stream>>>(gbuf, gcnt, colbase, row_ptr, col);

    const int AGG_BLOCKS = (N_NODES * 32 + 255) / 256;  // one half-wave per node
    const int MLP_BLOCKS = (N_NODES + 63) / 64;         // 1563 (ws rows padded)

    // ---- layer 1 ----
    agg_k<<<AGG_BLOCKS, 256, 0, stream>>>(hb, row_ptr, col, zbuf);
    mlp2_k<<<MLP_BLOCKS, 256, 0, stream>>>(zbuf, Whp, Wlp, Whp + 16384, Wlp + 16384,
                                           ba, bb, hb);
    // ---- layer 2 ----
    agg_k<<<AGG_BLOCKS, 256, 0, stream>>>(hb, row_ptr, col, zbuf);
    mlp2_k<<<MLP_BLOCKS, 256, 0, stream>>>(zbuf, Whp + 2 * 16384, Wlp + 2 * 16384,
                                           Whp + 3 * 16384, Wlp + 3 * 16384,
                                           ba + 128, bb + 128, hb);
    // ---- layer 3: MLP + fused final FC ----
    agg_k<<<AGG_BLOCKS, 256, 0, stream>>>(hb, row_ptr, col, zbuf);
    mlp3_k<<<MLP_BLOCKS, 256, 0, stream>>>(zbuf, Whp + 4 * 16384, Wlp + 4 * 16384,
                                           Whp + 5 * 16384, Wlp + 5 * 16384,
                                           ba + 256, bb + 256,
                                           fcWph, fcWpl, fcb, out);
}